// Round 8
// baseline (458.561 us; speedup 1.0000x reference)
//
#include <hip/hip_runtime.h>
#include <hip/hip_bf16.h>
#include <math.h>

#define N_NODES 50000
#define N_EDGES 800000
#define IN_DIM 32
#define HIDDEN 64
#define Z_DIM 32
#define SCAN_B 256
#define NB_SCAN ((N_NODES + SCAN_B - 1) / SCAN_B)   // 196

// bf16 (stored as ushort) <-> f32 helpers, RNE
__device__ __forceinline__ float bf2f(unsigned short u) {
    return __uint_as_float(((unsigned int)u) << 16);
}
__device__ __forceinline__ unsigned short f2bf(float f) {
    unsigned int u = __float_as_uint(f);
    u += 0x7fffu + ((u >> 16) & 1u);
    return (unsigned short)(u >> 16);
}

// ---------------------------------------------------------------------------
// prep: convert x to bf16, zero degree counters, detect edge_index dtype.
__global__ void prep_kernel(const float* __restrict__ x, unsigned short* __restrict__ xb,
                            const int* __restrict__ raw, int* __restrict__ flag,
                            int* __restrict__ cnt) {
    int i = blockIdx.x * 256 + threadIdx.x;
    if (i < N_NODES * IN_DIM) xb[i] = f2bf(x[i]);
    if (i < N_NODES) cnt[i] = 0;
    if (blockIdx.x == 0 && threadIdx.x < 64) {
        int odd = raw[2 * threadIdx.x + 1];
        unsigned long long b = __ballot(odd != 0);
        if (threadIdx.x == 0) *flag = (b == 0ULL) ? 1 : 0;
    }
}

// degree histogram straight off the raw edge_index (uniform branch on dtype)
__global__ void hist_kernel(const void* __restrict__ raw, const int* __restrict__ flag,
                            int* __restrict__ cnt) {
    int e = blockIdx.x * 256 + threadIdx.x;
    if (e >= N_EDGES) return;
    int d = (*flag) ? (int)((const long long*)raw)[N_EDGES + e]
                    : ((const int*)raw)[N_EDGES + e];
    atomicAdd(&cnt[d], 1);
}

// ---------------------------------------------------------------------------
// 3-phase exclusive scan over cnt -> rowptr; also dinv = rsqrt(deg+1).
__global__ void scan1_kernel(const int* __restrict__ cnt, int* __restrict__ pre,
                             int* __restrict__ bsum, float* __restrict__ dinv) {
    __shared__ int s[SCAN_B];
    int t = threadIdx.x;
    int g = blockIdx.x * SCAN_B + t;
    int v = (g < N_NODES) ? cnt[g] : 0;
    if (g < N_NODES) dinv[g] = rsqrtf((float)(v + 1));   // +1 self loop
    s[t] = v;
    __syncthreads();
    for (int o = 1; o < SCAN_B; o <<= 1) {
        int add = (t >= o) ? s[t - o] : 0;
        __syncthreads();
        s[t] += add;
        __syncthreads();
    }
    if (g < N_NODES) pre[g] = s[t] - v;
    if (t == SCAN_B - 1) bsum[blockIdx.x] = s[t];
}

__global__ void scan2_kernel(int* __restrict__ bsum, int nb) {   // single block
    __shared__ int s[256];
    int t = threadIdx.x;
    int v = (t < nb) ? bsum[t] : 0;
    s[t] = v;
    __syncthreads();
    for (int o = 1; o < 256; o <<= 1) {
        int add = (t >= o) ? s[t - o] : 0;
        __syncthreads();
        s[t] += add;
        __syncthreads();
    }
    if (t < nb) bsum[t] = s[t] - v;
}

__global__ void scan3_kernel(int* __restrict__ rowptr, const int* __restrict__ bsum,
                             int* __restrict__ cursor) {
    int g = blockIdx.x * SCAN_B + threadIdx.x;
    if (g < N_NODES) {
        int r = rowptr[g] + bsum[blockIdx.x];
        rowptr[g] = r;
        cursor[g] = r;
    }
    if (g == 0) rowptr[N_NODES] = N_EDGES;
}

// counting-sort scatter; emits packed (src, dinv[src]) per edge.
__global__ void scatter_kernel(const void* __restrict__ raw, const int* __restrict__ flag,
                               const float* __restrict__ dinv,
                               int* __restrict__ cursor, int2* __restrict__ ep) {
    int e = blockIdx.x * 256 + threadIdx.x;
    if (e >= N_EDGES) return;
    int s, d;
    if (*flag) {
        s = (int)((const long long*)raw)[e];
        d = (int)((const long long*)raw)[N_EDGES + e];
    } else {
        s = ((const int*)raw)[e];
        d = ((const int*)raw)[N_EDGES + e];
    }
    int p = atomicAdd(&cursor[d], 1);
    ep[p] = make_int2(s, __float_as_int(dinv[s]));
}

// ---------------------------------------------------------------------------
// Wave-cooperative aggregation over a bf16 table: srow[k] = (A h)[v][k],
// returned distributed lane==k (valid for lane < DIN).
// LPR = DIN/8 lanes per row (16B each); EPB = 64/LPR rows per batch; unroll U.
// Register-lean: U<=2 keeps live state ~14 regs so occupancy stays high.
template<int DIN, int U>
__device__ __forceinline__ float agg_row_bf(int v, const int* __restrict__ rowptr,
                                            const int2* __restrict__ ep,
                                            const float* __restrict__ dinv,
                                            const unsigned short* __restrict__ h) {
    const int LPR  = DIN / 8;          // 8 (D=64) / 4 (D=32)
    const int EPB  = 64 / LPR;         // 8 / 16
    const int STEP = EPB * U;
    int lane = threadIdx.x & 63;
    int q    = lane & (LPR - 1);
    int sub  = lane / LPR;
    int e0 = rowptr[v];
    int e1 = rowptr[v + 1];
    float acc[8];
#pragma unroll
    for (int j = 0; j < 8; j++) acc[j] = 0.0f;
    for (int e = e0; e < e1; e += STEP) {
        int2  pr[U];
        uint4 rv[U];
        float w[U];
#pragma unroll
        for (int u = 0; u < U; u++) {
            int ee = e + u * EPB + sub;
            pr[u] = ep[(ee < N_EDGES) ? ee : (N_EDGES - 1)];
        }
#pragma unroll
        for (int u = 0; u < U; u++) {
            int ee = e + u * EPB + sub;
            w[u]  = (ee < e1) ? __int_as_float(pr[u].y) : 0.0f;
            rv[u] = ((const uint4*)(h + (size_t)pr[u].x * DIN))[q];
        }
#pragma unroll
        for (int u = 0; u < U; u++) {
            unsigned int p0 = rv[u].x, p1 = rv[u].y, p2 = rv[u].z, p3 = rv[u].w;
            acc[0] = fmaf(w[u], __uint_as_float(p0 << 16),          acc[0]);
            acc[1] = fmaf(w[u], __uint_as_float(p0 & 0xffff0000u),  acc[1]);
            acc[2] = fmaf(w[u], __uint_as_float(p1 << 16),          acc[2]);
            acc[3] = fmaf(w[u], __uint_as_float(p1 & 0xffff0000u),  acc[3]);
            acc[4] = fmaf(w[u], __uint_as_float(p2 << 16),          acc[4]);
            acc[5] = fmaf(w[u], __uint_as_float(p2 & 0xffff0000u),  acc[5]);
            acc[6] = fmaf(w[u], __uint_as_float(p3 << 16),          acc[6]);
            acc[7] = fmaf(w[u], __uint_as_float(p3 & 0xffff0000u),  acc[7]);
        }
    }
#pragma unroll
    for (int o = LPR; o < 64; o <<= 1) {
#pragma unroll
        for (int j = 0; j < 8; j++) acc[j] += __shfl_xor(acc[j], o);
    }
    // lane k wants element (k&7) of acc[] held at source lane k>>3
    int srcl = lane >> 3;
    int c = lane & 7;
    float t0 = __shfl(acc[0], srcl);
    float t1 = __shfl(acc[1], srcl);
    float t2 = __shfl(acc[2], srcl);
    float t3 = __shfl(acc[3], srcl);
    float t4 = __shfl(acc[4], srcl);
    float t5 = __shfl(acc[5], srcl);
    float t6 = __shfl(acc[6], srcl);
    float t7 = __shfl(acc[7], srcl);
    float g = (c < 4) ? ((c < 2) ? (c == 0 ? t0 : t1) : (c == 2 ? t2 : t3))
                      : ((c < 6) ? (c == 4 ? t4 : t5) : (c == 6 ? t6 : t7));
    float dv = dinv[v];
    int hidx = (lane < DIN) ? lane : 0;
    float hk = bf2f(h[(size_t)v * DIN + hidx]);
    return dv * fmaf(dv, hk, g);                   // dv*(dv*h_v + sum w_s h_s)
}

// ---------------------------------------------------------------------------
// Fused layer: out[v][lane] = relu( (A h)[v][:] @ W[DIN,64] + b ), bf16 out.
// __launch_bounds__(256,8): force VGPR<=64 -> 8 blocks/CU residency.
template<int DIN>
__global__ __launch_bounds__(256, 8) void fused_layer_kernel(
        const int* __restrict__ rowptr, const int2* __restrict__ ep,
        const float* __restrict__ dinv, const unsigned short* __restrict__ h,
        const float* __restrict__ W, const float* __restrict__ b,
        unsigned short* __restrict__ out) {
    __shared__ float sW[DIN * 64];
    for (int i = threadIdx.x; i < DIN * 64; i += 256) sW[i] = W[i];
    __syncthreads();
    int lane = threadIdx.x & 63;
    float bb = b[lane];
    int wid = (blockIdx.x * blockDim.x + threadIdx.x) >> 6;
    int nw  = (gridDim.x * blockDim.x) >> 6;
    const int U = (DIN == 64) ? 2 : 1;             // 16 rows in flight either way
    for (int v = wid; v < N_NODES; v += nw) {
        float srow = agg_row_bf<DIN, U>(v, rowptr, ep, dinv, h);
        float a0 = 0.0f, a1 = 0.0f;                // 2-way ILP on the FMA chain
#pragma unroll
        for (int k = 0; k < DIN; k += 2) {
            a0 = fmaf(__shfl(srow, k),     sW[k * 64 + lane],       a0);
            a1 = fmaf(__shfl(srow, k + 1), sW[(k + 1) * 64 + lane], a1);
        }
        out[(size_t)v * 64 + lane] = f2bf(fmaxf(bb + a0 + a1, 0.0f));
    }
}

// Fused heads: a2 = (A h2)[v]; lanes<32 -> mu col, lanes>=32 -> lv col;
// z = mu + exp(0.5 lv)*eps. d_out = [z | mu | lv], fp32.
__global__ __launch_bounds__(256, 8) void fused_head_kernel(
        const int* __restrict__ rowptr, const int2* __restrict__ ep,
        const float* __restrict__ dinv, const unsigned short* __restrict__ h,
        const float* __restrict__ Wmu, const float* __restrict__ bmu,
        const float* __restrict__ Wlv, const float* __restrict__ blv,
        const float* __restrict__ eps, float* __restrict__ outz) {
    __shared__ float sW[64 * 64];                  // [k][0:32]=Wmu, [k][32:64]=Wlv
    for (int i = threadIdx.x; i < 64 * 64; i += 256) {
        int k = i >> 6, c = i & 63;
        sW[i] = (c < 32) ? Wmu[k * 32 + c] : Wlv[k * 32 + (c - 32)];
    }
    __syncthreads();
    int lane = threadIdx.x & 63;
    int f = lane & 31;
    bool hi = lane >= 32;
    float bb = hi ? blv[f] : bmu[f];
    float* z  = outz;
    float* mu = outz + (size_t)N_NODES * Z_DIM;
    float* lv = outz + 2 * (size_t)N_NODES * Z_DIM;
    int wid = (blockIdx.x * blockDim.x + threadIdx.x) >> 6;
    int nw  = (gridDim.x * blockDim.x) >> 6;
    for (int v = wid; v < N_NODES; v += nw) {
        float srow = agg_row_bf<64, 2>(v, rowptr, ep, dinv, h);
        float a0 = 0.0f, a1 = 0.0f;
#pragma unroll
        for (int k = 0; k < 64; k += 2) {
            a0 = fmaf(__shfl(srow, k),     sW[k * 64 + lane],       a0);
            a1 = fmaf(__shfl(srow, k + 1), sW[(k + 1) * 64 + lane], a1);
        }
        float acc = bb + a0 + a1;
        float t = expf(0.5f * acc) * eps[(size_t)v * Z_DIM + f];
        float tlo = __shfl(t, lane | 32);
        size_t o = (size_t)v * Z_DIM + f;
        if (!hi) { mu[o] = acc; z[o] = acc + tlo; }
        else     { lv[o] = acc; }
    }
}

// ---------------------------------------------------------------------------
extern "C" void kernel_launch(void* const* d_in, const int* in_sizes, int n_in,
                              void* d_out, int out_size, void* d_ws, size_t ws_size,
                              hipStream_t stream) {
    const float* x   = (const float*)d_in[0];
    const void*  ei  = d_in[1];
    const float* W1  = (const float*)d_in[2];
    const float* b1  = (const float*)d_in[3];
    const float* W2  = (const float*)d_in[4];
    const float* b2  = (const float*)d_in[5];
    const float* Wmu = (const float*)d_in[6];
    const float* bmu = (const float*)d_in[7];
    const float* Wlv = (const float*)d_in[8];
    const float* blv = (const float*)d_in[9];
    const float* eps = (const float*)d_in[10];
    float* out = (float*)d_out;
    (void)in_sizes; (void)n_in; (void)out_size; (void)ws_size;

    char* ws = (char*)d_ws;
    size_t off = 0;
    auto alloc = [&](size_t bytes) -> void* {
        void* p = ws + off;
        off += (bytes + 255) & ~(size_t)255;
        return p;
    };
    int2*           ep     = (int2*)alloc(sizeof(int2) * N_EDGES);   // 6.4 MB
    int*            rowptr = (int*)alloc(sizeof(int) * (N_NODES + 1));
    int*            cursor = (int*)alloc(sizeof(int) * N_NODES);
    int*            cnt    = (int*)alloc(sizeof(int) * N_NODES);
    float*          dinv   = (float*)alloc(sizeof(float) * N_NODES);
    int*            flag   = (int*)alloc(sizeof(int) * 64);
    int*            bsum   = (int*)alloc(sizeof(int) * 256);
    unsigned short* xb     = (unsigned short*)alloc(sizeof(short) * (size_t)N_NODES * IN_DIM);  // 3.2 MB
    unsigned short* h1     = (unsigned short*)alloc(sizeof(short) * (size_t)N_NODES * HIDDEN);  // 6.4 MB
    unsigned short* h2     = (unsigned short*)alloc(sizeof(short) * (size_t)N_NODES * HIDDEN);  // 6.4 MB

    prep_kernel<<<(N_NODES * IN_DIM + 255) / 256, 256, 0, stream>>>(x, xb, (const int*)ei, flag, cnt);
    hist_kernel<<<(N_EDGES + 255) / 256, 256, 0, stream>>>(ei, flag, cnt);
    scan1_kernel<<<NB_SCAN, SCAN_B, 0, stream>>>(cnt, rowptr, bsum, dinv);
    scan2_kernel<<<1, 256, 0, stream>>>(bsum, NB_SCAN);
    scan3_kernel<<<NB_SCAN, SCAN_B, 0, stream>>>(rowptr, bsum, cursor);
    scatter_kernel<<<(N_EDGES + 255) / 256, 256, 0, stream>>>(ei, flag, dinv, cursor, ep);

    const int FB = 2048;   // 8192 waves
    fused_layer_kernel<IN_DIM><<<FB, 256, 0, stream>>>(rowptr, ep, dinv, xb, W1, b1, h1);
    fused_layer_kernel<HIDDEN><<<FB, 256, 0, stream>>>(rowptr, ep, dinv, h1, W2, b2, h2);
    fused_head_kernel<<<FB, 256, 0, stream>>>(rowptr, ep, dinv, h2,
                                              Wmu, bmu, Wlv, blv, eps, out);
}

// Round 9
// 311.213 us; speedup vs baseline: 1.4735x; 1.4735x over previous
//
#include <hip/hip_runtime.h>
#include <hip/hip_bf16.h>
#include <math.h>

#define N_NODES 50000
#define N_EDGES 800000
#define IN_DIM 32
#define HIDDEN 64
#define Z_DIM 32
#define SCAN_B 256
#define NB_SCAN ((N_NODES + SCAN_B - 1) / SCAN_B)   // 196

// bf16 (stored as ushort) <-> f32 helpers, RNE
__device__ __forceinline__ float bf2f(unsigned short u) {
    return __uint_as_float(((unsigned int)u) << 16);
}
__device__ __forceinline__ unsigned short f2bf(float f) {
    unsigned int u = __float_as_uint(f);
    u += 0x7fffu + ((u >> 16) & 1u);
    return (unsigned short)(u >> 16);
}

// ---------------------------------------------------------------------------
// prep: convert x to bf16, zero degree counters, detect edge_index dtype.
__global__ void prep_kernel(const float* __restrict__ x, unsigned short* __restrict__ xb,
                            const int* __restrict__ raw, int* __restrict__ flag,
                            int* __restrict__ cnt) {
    int i = blockIdx.x * 256 + threadIdx.x;
    if (i < N_NODES * IN_DIM) xb[i] = f2bf(x[i]);
    if (i < N_NODES) cnt[i] = 0;
    if (blockIdx.x == 0 && threadIdx.x < 64) {
        int odd = raw[2 * threadIdx.x + 1];
        unsigned long long b = __ballot(odd != 0);
        if (threadIdx.x == 0) *flag = (b == 0ULL) ? 1 : 0;
    }
}

// degree histogram straight off the raw edge_index (uniform branch on dtype)
__global__ void hist_kernel(const void* __restrict__ raw, const int* __restrict__ flag,
                            int* __restrict__ cnt) {
    int e = blockIdx.x * 256 + threadIdx.x;
    if (e >= N_EDGES) return;
    int d = (*flag) ? (int)((const long long*)raw)[N_EDGES + e]
                    : ((const int*)raw)[N_EDGES + e];
    atomicAdd(&cnt[d], 1);
}

// ---------------------------------------------------------------------------
// 3-phase exclusive scan over cnt -> rowptr; also dinv = rsqrt(deg+1).
__global__ void scan1_kernel(const int* __restrict__ cnt, int* __restrict__ pre,
                             int* __restrict__ bsum, float* __restrict__ dinv) {
    __shared__ int s[SCAN_B];
    int t = threadIdx.x;
    int g = blockIdx.x * SCAN_B + t;
    int v = (g < N_NODES) ? cnt[g] : 0;
    if (g < N_NODES) dinv[g] = rsqrtf((float)(v + 1));   // +1 self loop
    s[t] = v;
    __syncthreads();
    for (int o = 1; o < SCAN_B; o <<= 1) {
        int add = (t >= o) ? s[t - o] : 0;
        __syncthreads();
        s[t] += add;
        __syncthreads();
    }
    if (g < N_NODES) pre[g] = s[t] - v;
    if (t == SCAN_B - 1) bsum[blockIdx.x] = s[t];
}

__global__ void scan2_kernel(int* __restrict__ bsum, int nb) {   // single block
    __shared__ int s[256];
    int t = threadIdx.x;
    int v = (t < nb) ? bsum[t] : 0;
    s[t] = v;
    __syncthreads();
    for (int o = 1; o < 256; o <<= 1) {
        int add = (t >= o) ? s[t - o] : 0;
        __syncthreads();
        s[t] += add;
        __syncthreads();
    }
    if (t < nb) bsum[t] = s[t] - v;
}

__global__ void scan3_kernel(int* __restrict__ rowptr, const int* __restrict__ bsum,
                             int* __restrict__ cursor) {
    int g = blockIdx.x * SCAN_B + threadIdx.x;
    if (g < N_NODES) {
        int r = rowptr[g] + bsum[blockIdx.x];
        rowptr[g] = r;
        cursor[g] = r;
    }
    if (g == 0) rowptr[N_NODES] = N_EDGES;
}

// counting-sort scatter; emits packed (src, dinv[src]) per edge.
__global__ void scatter_kernel(const void* __restrict__ raw, const int* __restrict__ flag,
                               const float* __restrict__ dinv,
                               int* __restrict__ cursor, int2* __restrict__ ep) {
    int e = blockIdx.x * 256 + threadIdx.x;
    if (e >= N_EDGES) return;
    int s, d;
    if (*flag) {
        s = (int)((const long long*)raw)[e];
        d = (int)((const long long*)raw)[N_EDGES + e];
    } else {
        s = ((const int*)raw)[e];
        d = ((const int*)raw)[N_EDGES + e];
    }
    int p = atomicAdd(&cursor[d], 1);
    ep[p] = make_int2(s, __float_as_int(dinv[s]));
}

// ---------------------------------------------------------------------------
// Dense GEMM: out[v][lane] = sum_k in[v][k] * W[k][lane].  (bias lives in agg)
// v is wave-uniform -> node row loads become scalar (SMEM) loads; W column in
// VGPRs; zero shuffles, zero LDS.
template<int DIN>
__global__ __launch_bounds__(256) void gemm_kernel(const unsigned short* __restrict__ in,
                                                   const float* __restrict__ W,
                                                   unsigned short* __restrict__ out) {
    int lane = threadIdx.x & 63;
    float wcol[DIN];
#pragma unroll
    for (int k = 0; k < DIN; k++) wcol[k] = W[k * 64 + lane];
    int wid = __builtin_amdgcn_readfirstlane((int)((blockIdx.x * blockDim.x + threadIdx.x) >> 6));
    int nw  = (gridDim.x * blockDim.x) >> 6;
    for (int v = wid; v < N_NODES; v += nw) {
        const uint4* rp = (const uint4*)(in + (size_t)v * DIN);   // uniform ptr
        float a0 = 0.0f, a1 = 0.0f;
#pragma unroll
        for (int c = 0; c < DIN / 8; c++) {
            uint4 r = rp[c];
            a0 = fmaf(__uint_as_float(r.x << 16),         wcol[c * 8 + 0], a0);
            a1 = fmaf(__uint_as_float(r.x & 0xffff0000u), wcol[c * 8 + 1], a1);
            a0 = fmaf(__uint_as_float(r.y << 16),         wcol[c * 8 + 2], a0);
            a1 = fmaf(__uint_as_float(r.y & 0xffff0000u), wcol[c * 8 + 3], a1);
            a0 = fmaf(__uint_as_float(r.z << 16),         wcol[c * 8 + 4], a0);
            a1 = fmaf(__uint_as_float(r.z & 0xffff0000u), wcol[c * 8 + 5], a1);
            a0 = fmaf(__uint_as_float(r.w << 16),         wcol[c * 8 + 6], a0);
            a1 = fmaf(__uint_as_float(r.w & 0xffff0000u), wcol[c * 8 + 7], a1);
        }
        out[(size_t)v * 64 + lane] = f2bf(a0 + a1);
    }
}

// Heads GEMM: out[v][lane] = h2[v][:] @ (lane<32 ? Wmu[:,lane] : Wlv[:,lane-32])
__global__ __launch_bounds__(256) void gemm_head_kernel(const unsigned short* __restrict__ in,
                                                        const float* __restrict__ Wmu,
                                                        const float* __restrict__ Wlv,
                                                        unsigned short* __restrict__ out) {
    int lane = threadIdx.x & 63;
    int f = lane & 31;
    float wcol[64];
#pragma unroll
    for (int k = 0; k < 64; k++)
        wcol[k] = (lane < 32) ? Wmu[k * 32 + f] : Wlv[k * 32 + f];
    int wid = __builtin_amdgcn_readfirstlane((int)((blockIdx.x * blockDim.x + threadIdx.x) >> 6));
    int nw  = (gridDim.x * blockDim.x) >> 6;
    for (int v = wid; v < N_NODES; v += nw) {
        const uint4* rp = (const uint4*)(in + (size_t)v * 64);
        float a0 = 0.0f, a1 = 0.0f;
#pragma unroll
        for (int c = 0; c < 8; c++) {
            uint4 r = rp[c];
            a0 = fmaf(__uint_as_float(r.x << 16),         wcol[c * 8 + 0], a0);
            a1 = fmaf(__uint_as_float(r.x & 0xffff0000u), wcol[c * 8 + 1], a1);
            a0 = fmaf(__uint_as_float(r.y << 16),         wcol[c * 8 + 2], a0);
            a1 = fmaf(__uint_as_float(r.y & 0xffff0000u), wcol[c * 8 + 3], a1);
            a0 = fmaf(__uint_as_float(r.z << 16),         wcol[c * 8 + 4], a0);
            a1 = fmaf(__uint_as_float(r.z & 0xffff0000u), wcol[c * 8 + 5], a1);
            a0 = fmaf(__uint_as_float(r.w << 16),         wcol[c * 8 + 6], a0);
            a1 = fmaf(__uint_as_float(r.w & 0xffff0000u), wcol[c * 8 + 7], a1);
        }
        out[(size_t)v * 64 + lane] = f2bf(a0 + a1);
    }
}

// ---------------------------------------------------------------------------
// Aggregation, lane = feature (D=64): out[v][f] = relu(dv*(dv*g[v][f] +
// sum_e w_e*g[s_e][f]) + b[f]).  One 128B line per edge, 2 readlanes/edge,
// no butterfly/redistribute/broadcast.
__global__ __launch_bounds__(256) void agg_layer_kernel(
        const int* __restrict__ rowptr, const int2* __restrict__ ep,
        const float* __restrict__ dinv, const unsigned short* __restrict__ g,
        const float* __restrict__ bias, unsigned short* __restrict__ out) {
    int lane = threadIdx.x & 63;
    float bb = bias[lane];
    int wid = __builtin_amdgcn_readfirstlane((int)((blockIdx.x * blockDim.x + threadIdx.x) >> 6));
    int nw  = (gridDim.x * blockDim.x) >> 6;
    for (int v = wid; v < N_NODES; v += nw) {
        int e0 = rowptr[v], e1 = rowptr[v + 1];     // uniform
        float dv = dinv[v];
        float acc = dv * bf2f(g[(size_t)v * 64 + lane]);
        for (int base = e0; base < e1; base += 64) {
            int idx = base + lane;
            int2 pr = ep[idx < N_EDGES ? idx : (N_EDGES - 1)];   // 64 edges, coalesced
            int cnt = e1 - base; cnt = cnt > 64 ? 64 : cnt;      // uniform
            int j = 0;
            for (; j + 8 <= cnt; j += 8) {
                float f[8], w[8];
#pragma unroll
                for (int u = 0; u < 8; u++) {
                    int   s = __builtin_amdgcn_readlane(pr.x, j + u);
                    w[u]    = __int_as_float(__builtin_amdgcn_readlane(pr.y, j + u));
                    f[u]    = bf2f(g[(size_t)s * 64 + lane]);    // independent loads
                }
#pragma unroll
                for (int u = 0; u < 8; u++) acc = fmaf(w[u], f[u], acc);
            }
            for (; j < cnt; j++) {
                int   s = __builtin_amdgcn_readlane(pr.x, j);
                float w = __int_as_float(__builtin_amdgcn_readlane(pr.y, j));
                acc = fmaf(w, bf2f(g[(size_t)s * 64 + lane]), acc);
            }
        }
        out[(size_t)v * 64 + lane] = f2bf(fmaxf(dv * acc + bb, 0.0f));
    }
}

// Head aggregation + reparam epilogue. gH packed [gmu | glv] per node.
// d_out = [z | mu | lv], fp32.
__global__ __launch_bounds__(256) void agg_head_kernel(
        const int* __restrict__ rowptr, const int2* __restrict__ ep,
        const float* __restrict__ dinv, const unsigned short* __restrict__ g,
        const float* __restrict__ bmu, const float* __restrict__ blv,
        const float* __restrict__ eps, float* __restrict__ outz) {
    int lane = threadIdx.x & 63;
    int f = lane & 31;
    bool hi = lane >= 32;
    float bb = hi ? blv[f] : bmu[f];
    float* z  = outz;
    float* mu = outz + (size_t)N_NODES * Z_DIM;
    float* lv = outz + 2 * (size_t)N_NODES * Z_DIM;
    int wid = __builtin_amdgcn_readfirstlane((int)((blockIdx.x * blockDim.x + threadIdx.x) >> 6));
    int nw  = (gridDim.x * blockDim.x) >> 6;
    for (int v = wid; v < N_NODES; v += nw) {
        int e0 = rowptr[v], e1 = rowptr[v + 1];
        float dv = dinv[v];
        float acc = dv * bf2f(g[(size_t)v * 64 + lane]);
        for (int base = e0; base < e1; base += 64) {
            int idx = base + lane;
            int2 pr = ep[idx < N_EDGES ? idx : (N_EDGES - 1)];
            int cnt = e1 - base; cnt = cnt > 64 ? 64 : cnt;
            int j = 0;
            for (; j + 8 <= cnt; j += 8) {
                float fv[8], w[8];
#pragma unroll
                for (int u = 0; u < 8; u++) {
                    int   s = __builtin_amdgcn_readlane(pr.x, j + u);
                    w[u]    = __int_as_float(__builtin_amdgcn_readlane(pr.y, j + u));
                    fv[u]   = bf2f(g[(size_t)s * 64 + lane]);
                }
#pragma unroll
                for (int u = 0; u < 8; u++) acc = fmaf(w[u], fv[u], acc);
            }
            for (; j < cnt; j++) {
                int   s = __builtin_amdgcn_readlane(pr.x, j);
                float w = __int_as_float(__builtin_amdgcn_readlane(pr.y, j));
                acc = fmaf(w, bf2f(g[(size_t)s * 64 + lane]), acc);
            }
        }
        float m = dv * acc + bb;                    // mu (lanes<32) / lv (hi)
        float t = expf(0.5f * m) * eps[(size_t)v * Z_DIM + f];
        float tlo = __shfl(t, lane | 32);
        size_t o = (size_t)v * Z_DIM + f;
        if (!hi) { mu[o] = m; z[o] = m + tlo; }
        else     { lv[o] = m; }
    }
}

// ---------------------------------------------------------------------------
extern "C" void kernel_launch(void* const* d_in, const int* in_sizes, int n_in,
                              void* d_out, int out_size, void* d_ws, size_t ws_size,
                              hipStream_t stream) {
    const float* x   = (const float*)d_in[0];
    const void*  ei  = d_in[1];
    const float* W1  = (const float*)d_in[2];
    const float* b1  = (const float*)d_in[3];
    const float* W2  = (const float*)d_in[4];
    const float* b2  = (const float*)d_in[5];
    const float* Wmu = (const float*)d_in[6];
    const float* bmu = (const float*)d_in[7];
    const float* Wlv = (const float*)d_in[8];
    const float* blv = (const float*)d_in[9];
    const float* eps = (const float*)d_in[10];
    float* out = (float*)d_out;
    (void)in_sizes; (void)n_in; (void)out_size; (void)ws_size;

    char* ws = (char*)d_ws;
    size_t off = 0;
    auto alloc = [&](size_t bytes) -> void* {
        void* p = ws + off;
        off += (bytes + 255) & ~(size_t)255;
        return p;
    };
    int2*           ep     = (int2*)alloc(sizeof(int2) * N_EDGES);   // 6.4 MB
    int*            rowptr = (int*)alloc(sizeof(int) * (N_NODES + 1));
    int*            cursor = (int*)alloc(sizeof(int) * N_NODES);
    int*            cnt    = (int*)alloc(sizeof(int) * N_NODES);
    float*          dinv   = (float*)alloc(sizeof(float) * N_NODES);
    int*            flag   = (int*)alloc(sizeof(int) * 64);
    int*            bsum   = (int*)alloc(sizeof(int) * 256);
    unsigned short* xb     = (unsigned short*)alloc(sizeof(short) * (size_t)N_NODES * IN_DIM);  // 3.2 MB
    unsigned short* G      = (unsigned short*)alloc(sizeof(short) * (size_t)N_NODES * HIDDEN);  // 6.4 MB
    unsigned short* H      = (unsigned short*)alloc(sizeof(short) * (size_t)N_NODES * HIDDEN);  // 6.4 MB

    prep_kernel<<<(N_NODES * IN_DIM + 255) / 256, 256, 0, stream>>>(x, xb, (const int*)ei, flag, cnt);
    hist_kernel<<<(N_EDGES + 255) / 256, 256, 0, stream>>>(ei, flag, cnt);
    scan1_kernel<<<NB_SCAN, SCAN_B, 0, stream>>>(cnt, rowptr, bsum, dinv);
    scan2_kernel<<<1, 256, 0, stream>>>(bsum, NB_SCAN);
    scan3_kernel<<<NB_SCAN, SCAN_B, 0, stream>>>(rowptr, bsum, cursor);
    scatter_kernel<<<(N_EDGES + 255) / 256, 256, 0, stream>>>(ei, flag, dinv, cursor, ep);

    const int FB = 2048;   // 8192 waves
    // Layer 1: g1 = x @ W1 ; h1 = relu(A g1 + b1)
    gemm_kernel<IN_DIM><<<FB, 256, 0, stream>>>(xb, W1, G);
    agg_layer_kernel<<<FB, 256, 0, stream>>>(rowptr, ep, dinv, G, b1, H);
    // Layer 2: g2 = h1 @ W2 ; h2 = relu(A g2 + b2)
    gemm_kernel<HIDDEN><<<FB, 256, 0, stream>>>(H, W2, G);
    agg_layer_kernel<<<FB, 256, 0, stream>>>(rowptr, ep, dinv, G, b2, H);
    // Heads: gH = h2 @ [Wmu|Wlv] ; [mu|lv] = A gH + b ; z = mu + exp(.5 lv) eps
    gemm_head_kernel<<<FB, 256, 0, stream>>>(H, Wmu, Wlv, G);
    agg_head_kernel<<<FB, 256, 0, stream>>>(rowptr, ep, dinv, G, bmu, blv, eps, out);
}